// Round 2
// baseline (1123.492 us; speedup 1.0000x reference)
//
#include <hip/hip_runtime.h>
#include <hip/hip_bf16.h>
#include <cstdint>
#include <cstddef>

#define N_F 128
#define N_HOPS 8
#define N_HID 256
#define N_CLS 64

typedef __bf16 bf16;
typedef __attribute__((ext_vector_type(8))) __bf16 bf16x8;
typedef __attribute__((ext_vector_type(4))) float f32x4;

__device__ inline f32x4 mfma16(bf16x8 a, bf16x8 b, f32x4 c) {
    return __builtin_amdgcn_mfma_f32_16x16x32_bf16(a, b, c, 0, 0, 0);
}

// ---------------------------------------------------------------------------
// Weight packing into MFMA B-operand fragment frames (used by k1 only now).
// Frame f = kt*NT + nt holds B[kt*32 .. +32)[nt*16 .. +16):
//   element (lane, j) = W[kt*32 + (lane>>4)*8 + j][nt*16 + (lane&15)]
// ---------------------------------------------------------------------------
__device__ inline void pack_one(const float* __restrict__ s, bf16* __restrict__ d,
                                int NC, int ntn, int idx) {
    const int lane = idx & 63;
    const int f = idx >> 6;
    const int kt = f / ntn, nt = f - kt * ntn;
    const int krow = kt * 32 + ((lane >> 4) << 3);
    const int col = nt * 16 + (lane & 15);
    const float* ss = s + (size_t)krow * NC + col;
    bf16* dd = d + ((size_t)f * 64 + lane) * 8;
#pragma unroll
    for (int j = 0; j < 8; ++j) dd[j] = (bf16)ss[(size_t)j * NC];
}

__global__ void pack_weights(const float* __restrict__ W1, const float* __restrict__ W2,
                             bf16* p1, bf16* p2) {
    int i = blockIdx.x * 256 + threadIdx.x;
    if (i < 32768) { pack_one(W1, p1, 256, 16, i); return; }   // 1024x256: 512 frames
    i -= 32768;
    if (i < 8192)  { pack_one(W2, p2, 256, 16, i); return; }   // 256x256: 128 frames
}

// ---------------------------------------------------------------------------
// K1 (unchanged bf16-MFMA): h1 = prelu(concat@W1+b1); jk = prelu(h1@W2+b2)
//     s_ref = jk . w_att_ref; s_x accumulated fp32 during A staging
//     wsm = softmax_h(sigmoid(s_x + s_ref + b_att))
// ---------------------------------------------------------------------------
__global__ __launch_bounds__(256) void k1_kernel(
    const float* __restrict__ feats, const bf16* __restrict__ w1p, const bf16* __restrict__ w2p,
    const float* __restrict__ b1, const float* __restrict__ b2,
    const float* __restrict__ a_jk_p, const float* __restrict__ a_main_p,
    const float* __restrict__ wref, const float* __restrict__ wax,
    const float* __restrict__ batt_p,
    float* __restrict__ wsm, int N)
{
    union __align__(16) U1 {
        struct { bf16 A[2048]; bf16 B[8192]; } s;   // phase 1: A frag-order + B frames
        bf16 H[64 * 264];                            // phase 2: h1 row-major (+8 pad)
    };
    __shared__ U1 u;
    __shared__ float sx[64 * 8];
    __shared__ float sref[64];

    const int t = threadIdx.x;
    const int lane = t & 63;
    const int wc = t >> 6;
    const int row0 = blockIdx.x * 64;

    for (int i = t; i < 64 * 8; i += 256) sx[i] = 0.f;
    if (t < 64) sref[t] = 0.f;
    __syncthreads();

    const int srow = t & 63;
    const int sc = t >> 6;
    const int grow = min(row0 + srow, N - 1);

    f32x4 acc[4][4] = {};

    for (int kt = 0; kt < 32; ++kt) {
        const int h = kt >> 2;
        const int f0 = ((kt & 3) << 5) + (sc << 3);
        const float* srcp = feats + ((size_t)h * N + grow) * N_F + f0;
        const float4 v0 = *(const float4*)srcp;
        const float4 v1 = *(const float4*)(srcp + 4);
        const float p = v0.x * wax[f0]     + v0.y * wax[f0 + 1] + v0.z * wax[f0 + 2] + v0.w * wax[f0 + 3]
                      + v1.x * wax[f0 + 4] + v1.y * wax[f0 + 5] + v1.z * wax[f0 + 6] + v1.w * wax[f0 + 7];
        atomicAdd(&sx[srow * 8 + h], p);
        bf16x8 av;
        av[0] = (bf16)v0.x; av[1] = (bf16)v0.y; av[2] = (bf16)v0.z; av[3] = (bf16)v0.w;
        av[4] = (bf16)v1.x; av[5] = (bf16)v1.y; av[6] = (bf16)v1.z; av[7] = (bf16)v1.w;
        *(bf16x8*)&u.s.A[((((srow >> 4) << 6) + (sc << 4) + (srow & 15))) << 3] = av;
        const bf16x8* bs = (const bf16x8*)(w1p + (size_t)kt * 8192);
        bf16x8* bd = (bf16x8*)u.s.B;
#pragma unroll
        for (int r = 0; r < 4; ++r) bd[t + 256 * r] = bs[t + 256 * r];
        __syncthreads();
        bf16x8 af[4], bfr[4];
#pragma unroll
        for (int i = 0; i < 4; ++i) af[i] = *(bf16x8*)&u.s.A[((i << 6) + lane) << 3];
#pragma unroll
        for (int j = 0; j < 4; ++j) bfr[j] = *(bf16x8*)&u.s.B[(((wc << 2) + j) * 64 + lane) << 3];
#pragma unroll
        for (int i = 0; i < 4; ++i)
#pragma unroll
            for (int j = 0; j < 4; ++j)
                acc[i][j] = mfma16(af[i], bfr[j], acc[i][j]);
        __syncthreads();
    }

    const float ajk = *a_jk_p;
#pragma unroll
    for (int j = 0; j < 4; ++j) {
        const int colg = (wc << 6) + (j << 4) + (lane & 15);
        const float bias = b1[colg];
#pragma unroll
        for (int i = 0; i < 4; ++i)
#pragma unroll
            for (int r = 0; r < 4; ++r) {
                const int row = (i << 4) + ((lane >> 4) << 2) + r;
                float v = acc[i][j][r] + bias;
                v = v >= 0.f ? v : ajk * v;
                u.H[row * 264 + colg] = (bf16)v;
            }
    }
    __syncthreads();

    f32x4 acc2[4][4] = {};
    for (int kt = 0; kt < 8; ++kt) {
        bf16x8 af[4], bfr[4];
#pragma unroll
        for (int i = 0; i < 4; ++i)
            af[i] = *(bf16x8*)&u.H[((i << 4) + (lane & 15)) * 264 + (kt << 5) + ((lane >> 4) << 3)];
#pragma unroll
        for (int j = 0; j < 4; ++j)
            bfr[j] = *(const bf16x8*)&w2p[((size_t)((kt << 4) + (wc << 2) + j) * 64 + lane) * 8];
#pragma unroll
        for (int i = 0; i < 4; ++i)
#pragma unroll
            for (int j = 0; j < 4; ++j)
                acc2[i][j] = mfma16(af[i], bfr[j], acc2[i][j]);
    }

    const float amain = *a_main_p;
    float pr[4][4] = {};
#pragma unroll
    for (int j = 0; j < 4; ++j) {
        const int colg = (wc << 6) + (j << 4) + (lane & 15);
        const float bias = b2[colg];
        const float wr_ = wref[colg];
#pragma unroll
        for (int i = 0; i < 4; ++i)
#pragma unroll
            for (int r = 0; r < 4; ++r) {
                float v = acc2[i][j][r] + bias;
                v = v >= 0.f ? v : amain * v;
                pr[i][r] += v * wr_;
            }
    }
#pragma unroll
    for (int m = 1; m < 16; m <<= 1)
#pragma unroll
        for (int i = 0; i < 4; ++i)
#pragma unroll
            for (int r = 0; r < 4; ++r)
                pr[i][r] += __shfl_xor(pr[i][r], m, 64);
    if ((lane & 15) == 0) {
#pragma unroll
        for (int i = 0; i < 4; ++i)
#pragma unroll
            for (int r = 0; r < 4; ++r)
                atomicAdd(&sref[(i << 4) + ((lane >> 4) << 2) + r], pr[i][r]);
    }
    __syncthreads();

    if (t < 64) {
        const int rg = row0 + t;
        if (rg < N) {
            const float sr = sref[t] + *batt_p;
            float e[8], mx = -1e30f;
#pragma unroll
            for (int h = 0; h < 8; ++h) {
                const float s = 1.f / (1.f + expf(-(sx[t * 8 + h] + sr)));
                e[h] = s; mx = fmaxf(mx, s);
            }
            float sum = 0.f;
#pragma unroll
            for (int h = 0; h < 8; ++h) { e[h] = expf(e[h] - mx); sum += e[h]; }
            const float inv = 1.f / sum;
#pragma unroll
            for (int h = 0; h < 8; ++h) wsm[(size_t)rg * 8 + h] = e[h] * inv;
        }
    }
}

// ---------------------------------------------------------------------------
// K2 — DIAGNOSTIC pure-fp32 VALU version (no bf16, no MFMA, no layout tricks):
//   agg = sum_h wsm[:,h]*feats[h];  out = prelu(agg@O1+bo1, a_out)@O2 + bo2
// Per block: 32 rows, 256 threads (4 waves).
// ---------------------------------------------------------------------------
__global__ __launch_bounds__(256) void k2_kernel(
    const float* __restrict__ feats, const float* __restrict__ wsm,
    const float* __restrict__ O1, const float* __restrict__ O2,
    const float* __restrict__ bo1, const float* __restrict__ a_out_p,
    const float* __restrict__ bo2, float* __restrict__ out, int N)
{
    union __align__(16) U2 {
        struct { float AG[32 * 132]; float B[16 * 260]; } p;  // agg + O1 chunk
        float HO[32 * 260];                                    // h_o fp32
    };
    __shared__ U2 u;
    __shared__ float sB2[32 * 68];   // O2 k-chunk
    __shared__ float swl[256];       // 32 rows x 8 hops

    const int t = threadIdx.x;
    const int lane = t & 63;
    const int w = t >> 6;
    const int row0 = blockIdx.x * 32;

    {
        const int rg = min(row0 + (t >> 3), N - 1);
        swl[t] = wsm[(size_t)rg * 8 + (t & 7)];
    }
    __syncthreads();

    // ---- weighted hop aggregation (fp32) -> AG[32][132] row-major ----
    {
        const int r = t >> 3, c8 = t & 7;
        const int rg = min(row0 + r, N - 1);
        float a[16] = {};
#pragma unroll
        for (int h = 0; h < 8; ++h) {
            const float wgt = swl[r * 8 + h];
            const float* p = feats + ((size_t)h * N + rg) * N_F + c8 * 16;
#pragma unroll
            for (int q = 0; q < 4; ++q) {
                const f32x4 v = *(const f32x4*)(p + q * 4);
                a[q * 4 + 0] += wgt * v.x; a[q * 4 + 1] += wgt * v.y;
                a[q * 4 + 2] += wgt * v.z; a[q * 4 + 3] += wgt * v.w;
            }
        }
#pragma unroll
        for (int q = 0; q < 4; ++q) {
            f32x4 v; v.x = a[q * 4]; v.y = a[q * 4 + 1]; v.z = a[q * 4 + 2]; v.w = a[q * 4 + 3];
            *(f32x4*)&u.p.AG[r * 132 + c8 * 16 + q * 4] = v;
        }
    }
    __syncthreads();

    // ---- GEMM3 (fp32): h_o = prelu(agg @ O1 + bo1, a_out) ----
    // wave w -> rows [w*8, +8); lane -> cols [lane*4, +4); K chunked by 16.
    f32x4 acc[8] = {};
    for (int kc = 0; kc < 8; ++kc) {
        {
            const int kr = t >> 4, c = (t & 15) * 16;
            const float* src = O1 + (size_t)(kc * 16 + kr) * 256 + c;
#pragma unroll
            for (int q = 0; q < 4; ++q)
                *(f32x4*)&u.p.B[kr * 260 + c + q * 4] = *(const f32x4*)(src + q * 4);
        }
        __syncthreads();
#pragma unroll
        for (int k4 = 0; k4 < 4; ++k4) {
            f32x4 a4[8], b4[4];
#pragma unroll
            for (int rr = 0; rr < 8; ++rr)
                a4[rr] = *(const f32x4*)&u.p.AG[(w * 8 + rr) * 132 + kc * 16 + k4 * 4];
#pragma unroll
            for (int kk = 0; kk < 4; ++kk)
                b4[kk] = *(const f32x4*)&u.p.B[(k4 * 4 + kk) * 260 + lane * 4];
#pragma unroll
            for (int rr = 0; rr < 8; ++rr)
                acc[rr] += a4[rr].x * b4[0] + a4[rr].y * b4[1] + a4[rr].z * b4[2] + a4[rr].w * b4[3];
        }
        __syncthreads();
    }

    // ---- epilogue: prelu -> HO (aliases AG/B; all reads complete per barrier above) ----
    {
        const float aout = *a_out_p;
        const f32x4 bias = *(const f32x4*)&bo1[lane * 4];
#pragma unroll
        for (int rr = 0; rr < 8; ++rr) {
            f32x4 v = acc[rr] + bias;
            v.x = v.x >= 0.f ? v.x : aout * v.x;
            v.y = v.y >= 0.f ? v.y : aout * v.y;
            v.z = v.z >= 0.f ? v.z : aout * v.z;
            v.w = v.w >= 0.f ? v.w : aout * v.w;
            *(f32x4*)&u.HO[(w * 8 + rr) * 260 + lane * 4] = v;
        }
    }
    __syncthreads();

    // ---- GEMM4 (fp32): out = h_o @ O2 + bo2 ----
    // wave w -> rows [w*8, +8); lane -> col lane; K chunked by 32.
    float acc2[8] = {};
    for (int kc = 0; kc < 8; ++kc) {
        {
            const int kr = t >> 3, c8 = (t & 7) * 8;
            const float* src = O2 + (size_t)(kc * 32 + kr) * 64 + c8;
            *(f32x4*)&sB2[kr * 68 + c8]     = *(const f32x4*)src;
            *(f32x4*)&sB2[kr * 68 + c8 + 4] = *(const f32x4*)(src + 4);
        }
        __syncthreads();
#pragma unroll
        for (int k4 = 0; k4 < 8; ++k4) {
            f32x4 a4[8];
#pragma unroll
            for (int rr = 0; rr < 8; ++rr)
                a4[rr] = *(const f32x4*)&u.HO[(w * 8 + rr) * 260 + kc * 32 + k4 * 4];
            const float b0 = sB2[(k4 * 4 + 0) * 68 + lane];
            const float b1 = sB2[(k4 * 4 + 1) * 68 + lane];
            const float b2 = sB2[(k4 * 4 + 2) * 68 + lane];
            const float b3 = sB2[(k4 * 4 + 3) * 68 + lane];
#pragma unroll
            for (int rr = 0; rr < 8; ++rr)
                acc2[rr] += a4[rr].x * b0 + a4[rr].y * b1 + a4[rr].z * b2 + a4[rr].w * b3;
        }
        __syncthreads();
    }

    {
        const float bv = bo2[lane];
#pragma unroll
        for (int rr = 0; rr < 8; ++rr) {
            const int rg = row0 + w * 8 + rr;
            if (rg < N) out[(size_t)rg * 64 + lane] = acc2[rr] + bv;
        }
    }
}

extern "C" void kernel_launch(void* const* d_in, const int* in_sizes, int n_in,
                              void* d_out, int out_size, void* d_ws, size_t ws_size,
                              hipStream_t stream) {
    const float* feats  = (const float*)d_in[0];
    const float* W1     = (const float*)d_in[1];
    const float* b1     = (const float*)d_in[2];
    const float* W2     = (const float*)d_in[3];
    const float* b2     = (const float*)d_in[4];
    const float* a_jk   = (const float*)d_in[5];
    const float* a_main = (const float*)d_in[6];
    const float* a_out  = (const float*)d_in[7];
    const float* wref   = (const float*)d_in[8];
    const float* wax    = (const float*)d_in[9];
    const float* batt   = (const float*)d_in[10];
    const float* O1     = (const float*)d_in[11];
    const float* bo1    = (const float*)d_in[12];
    const float* O2     = (const float*)d_in[13];
    const float* bo2    = (const float*)d_in[14];

    const int N = in_sizes[0] / (N_HOPS * N_F);

    char* ws = (char*)d_ws;
    bf16* p1 = (bf16*)ws;                   // 524288 B  (W_jk1 packed)
    bf16* p2 = (bf16*)(ws + 524288);        // 131072 B  (W_jk2 packed)
    float* wsm = (float*)(ws + 655360);     // N*8*4 B   (softmax hop weights)

    pack_weights<<<160, 256, 0, stream>>>(W1, W2, p1, p2);
    const int nb1 = (N + 63) / 64;
    k1_kernel<<<nb1, 256, 0, stream>>>(feats, p1, p2, b1, b2, a_jk, a_main,
                                       wref, wax, batt, wsm, N);
    const int nb2 = (N + 31) / 32;
    k2_kernel<<<nb2, 256, 0, stream>>>(feats, wsm, O1, O2, bo1, a_out, bo2,
                                       (float*)d_out, N);
}

// Round 3
// 762.472 us; speedup vs baseline: 1.4735x; 1.4735x over previous
//
#include <hip/hip_runtime.h>
#include <hip/hip_bf16.h>
#include <cstdint>
#include <cstddef>

#define N_F 128
#define N_HOPS 8
#define N_HID 256
#define N_CLS 64

typedef __bf16 bf16;
typedef __attribute__((ext_vector_type(8))) __bf16 bf16x8;
typedef __attribute__((ext_vector_type(4))) float f32x4;

__device__ inline f32x4 mfma16(bf16x8 a, bf16x8 b, f32x4 c) {
    return __builtin_amdgcn_mfma_f32_16x16x32_bf16(a, b, c, 0, 0, 0);
}

typedef const __attribute__((address_space(1))) unsigned int guint;
typedef __attribute__((address_space(3))) unsigned int luint;
__device__ __forceinline__ void gl_lds16(const void* g, void* l) {
    // async global->LDS, 16 B per lane (wave-uniform base + lane*16)
    __builtin_amdgcn_global_load_lds((guint*)g, (luint*)l, 16, 0, 0);
}

// ---------------------------------------------------------------------------
// Weight packing into MFMA B-operand fragment frames.
// Frame f = kt*NT + nt holds B[kt*32 .. +32)[nt*16 .. +16):
//   element (lane, j) = W[kt*32 + (lane>>4)*8 + j][nt*16 + (lane&15)]
// stored at d[(f*64 + lane)*8 + j].
// ---------------------------------------------------------------------------
__device__ inline void pack_one(const float* __restrict__ s, bf16* __restrict__ d,
                                int NC, int ntn, int idx) {
    const int lane = idx & 63;
    const int f = idx >> 6;
    const int kt = f / ntn, nt = f - kt * ntn;
    const int krow = kt * 32 + ((lane >> 4) << 3);
    const int col = nt * 16 + (lane & 15);
    const float* ss = s + (size_t)krow * NC + col;
    bf16* dd = d + ((size_t)f * 64 + lane) * 8;
#pragma unroll
    for (int j = 0; j < 8; ++j) dd[j] = (bf16)ss[(size_t)j * NC];
}

__global__ void pack_weights(const float* __restrict__ W1, const float* __restrict__ W2,
                             const float* __restrict__ O1, const float* __restrict__ O2,
                             bf16* p1, bf16* p2, bf16* p3, bf16* p4) {
    int i = blockIdx.x * 256 + threadIdx.x;
    if (i < 32768) { pack_one(W1, p1, 256, 16, i); return; }   // 1024x256: 512 frames
    i -= 32768;
    if (i < 8192)  { pack_one(W2, p2, 256, 16, i); return; }   // 256x256: 128 frames
    i -= 8192;
    if (i < 4096)  { pack_one(O1, p3, 256, 16, i); return; }   // 128x256: 64 frames
    i -= 4096;
    if (i < 2048)  { pack_one(O2, p4, 64, 4, i); return; }     // 256x64: 32 frames
}

// ---------------------------------------------------------------------------
// K1: 64 rows/block, 256 thr (4 waves, wave wc -> cols [wc*64,+64)).
// h1 = prelu(concat@W1+b1); jk = prelu(h1@W2+b2); s_ref = jk.w_att_ref;
// s_x[h] accumulated fp32 during A staging; wsm = softmax(sigmoid(...)).
// Change vs verified R2 version: B staged via global_load_lds (async DMA,
// no VGPR round-trip) and s_x atomics batched 4x. Everything else identical.
// ---------------------------------------------------------------------------
__global__ __launch_bounds__(256) void k1_kernel(
    const float* __restrict__ feats, const bf16* __restrict__ w1p, const bf16* __restrict__ w2p,
    const float* __restrict__ b1, const float* __restrict__ b2,
    const float* __restrict__ a_jk_p, const float* __restrict__ a_main_p,
    const float* __restrict__ wref, const float* __restrict__ wax,
    const float* __restrict__ batt_p,
    float* __restrict__ wsm, int N)
{
    union __align__(16) U1 {
        struct { bf16 A[2048]; bf16 B[8192]; } s;   // phase 1: A frag-order + B frames
        bf16 H[64 * 264];                            // phase 2: h1 row-major (+8 pad)
    };
    __shared__ U1 u;
    __shared__ float sx[64 * 8];
    __shared__ float sref[64];

    const int t = threadIdx.x;
    const int lane = t & 63;
    const int wc = t >> 6;
    const int row0 = blockIdx.x * 64;

    for (int i = t; i < 64 * 8; i += 256) sx[i] = 0.f;
    if (t < 64) sref[t] = 0.f;
    __syncthreads();

    const int srow = t & 63;
    const int sc = t >> 6;
    const int grow = min(row0 + srow, N - 1);

    f32x4 acc[4][4] = {};
    float pacc = 0.f;

    for (int kt = 0; kt < 32; ++kt) {
        // ---- stage A tile 64x32 (fp32 -> bf16, fragment order) + s_x partial ----
        const int h = kt >> 2;
        const int f0 = ((kt & 3) << 5) + (sc << 3);
        const float* srcp = feats + ((size_t)h * N + grow) * N_F + f0;
        const float4 v0 = *(const float4*)srcp;
        const float4 v1 = *(const float4*)(srcp + 4);
        pacc += v0.x * wax[f0]     + v0.y * wax[f0 + 1] + v0.z * wax[f0 + 2] + v0.w * wax[f0 + 3]
              + v1.x * wax[f0 + 4] + v1.y * wax[f0 + 5] + v1.z * wax[f0 + 6] + v1.w * wax[f0 + 7];
        if ((kt & 3) == 3) { atomicAdd(&sx[srow * 8 + h], pacc); pacc = 0.f; }
        bf16x8 av;
        av[0] = (bf16)v0.x; av[1] = (bf16)v0.y; av[2] = (bf16)v0.z; av[3] = (bf16)v0.w;
        av[4] = (bf16)v1.x; av[5] = (bf16)v1.y; av[6] = (bf16)v1.z; av[7] = (bf16)v1.w;
        *(bf16x8*)&u.s.A[((((srow >> 4) << 6) + (sc << 4) + (srow & 15))) << 3] = av;
        // ---- stage B: 16 KB pre-packed frames, async global->LDS (4 x 4 KB) ----
        const bf16* bsrc = w1p + (size_t)kt * 8192;
#pragma unroll
        for (int r = 0; r < 4; ++r)
            gl_lds16(bsrc + r * 2048 + t * 8, &u.s.B[r * 2048 + t * 8]);
        __syncthreads();   // drains vmcnt (incl. global_load_lds) + lds writes
        // ---- fragments + 16 MFMA ----
        bf16x8 af[4], bfr[4];
#pragma unroll
        for (int i = 0; i < 4; ++i) af[i] = *(bf16x8*)&u.s.A[((i << 6) + lane) << 3];
#pragma unroll
        for (int j = 0; j < 4; ++j) bfr[j] = *(bf16x8*)&u.s.B[(((wc << 2) + j) * 64 + lane) << 3];
#pragma unroll
        for (int i = 0; i < 4; ++i)
#pragma unroll
            for (int j = 0; j < 4; ++j)
                acc[i][j] = mfma16(af[i], bfr[j], acc[i][j]);
        __syncthreads();
    }

    // ---- epilogue 1: h1 = prelu(acc + b1, a_jk) -> H row-major ----
    const float ajk = *a_jk_p;
#pragma unroll
    for (int j = 0; j < 4; ++j) {
        const int colg = (wc << 6) + (j << 4) + (lane & 15);
        const float bias = b1[colg];
#pragma unroll
        for (int i = 0; i < 4; ++i)
#pragma unroll
            for (int r = 0; r < 4; ++r) {
                const int row = (i << 4) + ((lane >> 4) << 2) + r;
                float v = acc[i][j][r] + bias;
                v = v >= 0.f ? v : ajk * v;
                u.H[row * 264 + colg] = (bf16)v;
            }
    }
    __syncthreads();

    // ---- GEMM2: jk = prelu(h1 @ W2 + b2, a_main); s_ref partials ----
    f32x4 acc2[4][4] = {};
    for (int kt = 0; kt < 8; ++kt) {
        bf16x8 af[4], bfr[4];
#pragma unroll
        for (int i = 0; i < 4; ++i)
            af[i] = *(bf16x8*)&u.H[((i << 4) + (lane & 15)) * 264 + (kt << 5) + ((lane >> 4) << 3)];
#pragma unroll
        for (int j = 0; j < 4; ++j)
            bfr[j] = *(const bf16x8*)&w2p[((size_t)((kt << 4) + (wc << 2) + j) * 64 + lane) * 8];
#pragma unroll
        for (int i = 0; i < 4; ++i)
#pragma unroll
            for (int j = 0; j < 4; ++j)
                acc2[i][j] = mfma16(af[i], bfr[j], acc2[i][j]);
    }

    const float amain = *a_main_p;
    float pr[4][4] = {};
#pragma unroll
    for (int j = 0; j < 4; ++j) {
        const int colg = (wc << 6) + (j << 4) + (lane & 15);
        const float bias = b2[colg];
        const float wr_ = wref[colg];
#pragma unroll
        for (int i = 0; i < 4; ++i)
#pragma unroll
            for (int r = 0; r < 4; ++r) {
                float v = acc2[i][j][r] + bias;
                v = v >= 0.f ? v : amain * v;
                pr[i][r] += v * wr_;
            }
    }
#pragma unroll
    for (int m = 1; m < 16; m <<= 1)
#pragma unroll
        for (int i = 0; i < 4; ++i)
#pragma unroll
            for (int r = 0; r < 4; ++r)
                pr[i][r] += __shfl_xor(pr[i][r], m, 64);
    if ((lane & 15) == 0) {
#pragma unroll
        for (int i = 0; i < 4; ++i)
#pragma unroll
            for (int r = 0; r < 4; ++r)
                atomicAdd(&sref[(i << 4) + ((lane >> 4) << 2) + r], pr[i][r]);
    }
    __syncthreads();

    // ---- scores -> sigmoid -> softmax over hops -> wsm ----
    if (t < 64) {
        const int rg = row0 + t;
        if (rg < N) {
            const float sr = sref[t] + *batt_p;
            float e[8], mx = -1e30f;
#pragma unroll
            for (int h = 0; h < 8; ++h) {
                const float s = 1.f / (1.f + expf(-(sx[t * 8 + h] + sr)));
                e[h] = s; mx = fmaxf(mx, s);
            }
            float sum = 0.f;
#pragma unroll
            for (int h = 0; h < 8; ++h) { e[h] = expf(e[h] - mx); sum += e[h]; }
            const float inv = 1.f / sum;
#pragma unroll
            for (int h = 0; h < 8; ++h) wsm[(size_t)rg * 8 + h] = e[h] * inv;
        }
    }
}

// ---------------------------------------------------------------------------
// K2 v3 (bf16 MFMA, built ONLY from k1-verified patterns):
//   agg = sum_h wsm[:,h]*feats[h]  (fp32, then bf16 row-major padded LDS)
//   h_o = prelu(agg@O1+bo1, a_out) (GEMM3: k1-GEMM2 pattern; HO row-major)
//   out = h_o@O2 + bo2            (GEMM4: wave cg -> cols [cg*16,+16))
// 64 rows/block, 256 threads (4 waves).
// ---------------------------------------------------------------------------
__global__ __launch_bounds__(256) void k2_kernel(
    const float* __restrict__ feats, const float* __restrict__ wsm,
    const bf16* __restrict__ o1p, const bf16* __restrict__ o2p,
    const float* __restrict__ bo1, const float* __restrict__ a_out_p,
    const float* __restrict__ bo2, float* __restrict__ out, int N)
{
    union __align__(16) U2 {
        bf16 AG[64 * 136];   // agg bf16 row-major, 128 cols (+8 pad)
        bf16 HO[64 * 264];   // h_o bf16 row-major, 256 cols (+8 pad)
    };
    __shared__ U2 u;
    __shared__ float wsl[512];

    const int t = threadIdx.x;
    const int lane = t & 63;
    const int cg = t >> 6;                 // wave = col group
    const int row0 = blockIdx.x * 64;

    for (int i = t; i < 512; i += 256) {
        const int rg = min(row0 + (i >> 3), N - 1);
        wsl[i] = wsm[(size_t)rg * 8 + (i & 7)];
    }
    __syncthreads();

    // ---- weighted hop aggregation (fp32) -> AG bf16 row-major ----
    {
        const int r = t >> 2;              // row 0..63
        const int c = t & 3;               // 32-feature chunk
        const int rg = min(row0 + r, N - 1);
        f32x4 a4[8] = {};
#pragma unroll
        for (int h = 0; h < 8; ++h) {
            const float wgt = wsl[r * 8 + h];
            const f32x4* p4 = (const f32x4*)(feats + ((size_t)h * N + rg) * N_F + c * 32);
#pragma unroll
            for (int q = 0; q < 8; ++q) a4[q] += wgt * p4[q];
        }
#pragma unroll
        for (int q2 = 0; q2 < 4; ++q2) {
            bf16x8 av;
#pragma unroll
            for (int e = 0; e < 4; ++e) {
                av[e] = (bf16)a4[q2 * 2][e];
                av[4 + e] = (bf16)a4[q2 * 2 + 1][e];
            }
            *(bf16x8*)&u.AG[r * 136 + c * 32 + q2 * 8] = av;
        }
    }
    __syncthreads();

    // ---- GEMM3: h_o = prelu(agg @ O1 + bo1, a_out)  [K=128 -> 4 kt] ----
    f32x4 acc3[4][4] = {};
    for (int kt = 0; kt < 4; ++kt) {
        bf16x8 af[4], bfr[4];
#pragma unroll
        for (int i = 0; i < 4; ++i)
            af[i] = *(bf16x8*)&u.AG[((i << 4) + (lane & 15)) * 136 + (kt << 5) + ((lane >> 4) << 3)];
#pragma unroll
        for (int j = 0; j < 4; ++j)
            bfr[j] = *(const bf16x8*)&o1p[((size_t)((kt << 4) + (cg << 2) + j) * 64 + lane) * 8];
#pragma unroll
        for (int i = 0; i < 4; ++i)
#pragma unroll
            for (int j = 0; j < 4; ++j)
                acc3[i][j] = mfma16(af[i], bfr[j], acc3[i][j]);
    }
    __syncthreads();   // all AG reads done before HO overwrites the union

    const float aout = *a_out_p;
#pragma unroll
    for (int j = 0; j < 4; ++j) {
        const int colg = (cg << 6) + (j << 4) + (lane & 15);
        const float bias = bo1[colg];
#pragma unroll
        for (int i = 0; i < 4; ++i)
#pragma unroll
            for (int r = 0; r < 4; ++r) {
                const int row = (i << 4) + ((lane >> 4) << 2) + r;
                float v = acc3[i][j][r] + bias;
                v = v >= 0.f ? v : aout * v;
                u.HO[row * 264 + colg] = (bf16)v;
            }
    }
    __syncthreads();

    // ---- GEMM4: out = h_o @ O2 + bo2  [K=256 -> 8 kt; wave cg -> 16 cols] ----
    f32x4 acc4[4] = {};
    for (int kt = 0; kt < 8; ++kt) {
        const bf16x8 b = *(const bf16x8*)&o2p[((size_t)((kt << 2) + cg) * 64 + lane) * 8];
#pragma unroll
        for (int i = 0; i < 4; ++i) {
            const bf16x8 a = *(bf16x8*)&u.HO[((i << 4) + (lane & 15)) * 264 + (kt << 5) + ((lane >> 4) << 3)];
            acc4[i] = mfma16(a, b, acc4[i]);
        }
    }
    {
        const int colg = (cg << 4) + (lane & 15);
        const float bv = bo2[colg];
#pragma unroll
        for (int i = 0; i < 4; ++i)
#pragma unroll
            for (int r = 0; r < 4; ++r) {
                const int rg = row0 + (i << 4) + ((lane >> 4) << 2) + r;
                if (rg < N) out[(size_t)rg * 64 + colg] = acc4[i][r] + bv;
            }
    }
}

extern "C" void kernel_launch(void* const* d_in, const int* in_sizes, int n_in,
                              void* d_out, int out_size, void* d_ws, size_t ws_size,
                              hipStream_t stream) {
    const float* feats  = (const float*)d_in[0];
    const float* W1     = (const float*)d_in[1];
    const float* b1     = (const float*)d_in[2];
    const float* W2     = (const float*)d_in[3];
    const float* b2     = (const float*)d_in[4];
    const float* a_jk   = (const float*)d_in[5];
    const float* a_main = (const float*)d_in[6];
    const float* a_out  = (const float*)d_in[7];
    const float* wref   = (const float*)d_in[8];
    const float* wax    = (const float*)d_in[9];
    const float* batt   = (const float*)d_in[10];
    const float* O1     = (const float*)d_in[11];
    const float* bo1    = (const float*)d_in[12];
    const float* O2     = (const float*)d_in[13];
    const float* bo2    = (const float*)d_in[14];

    const int N = in_sizes[0] / (N_HOPS * N_F);

    char* ws = (char*)d_ws;
    bf16* p1 = (bf16*)ws;                   // 524288 B  (W_jk1 packed)
    bf16* p2 = (bf16*)(ws + 524288);        // 131072 B  (W_jk2 packed)
    bf16* p3 = (bf16*)(ws + 655360);        // 65536 B   (W_o1 packed)
    bf16* p4 = (bf16*)(ws + 720896);        // 32768 B   (W_o2 packed)
    float* wsm = (float*)(ws + 753664);     // N*8*4 B   (softmax hop weights)

    pack_weights<<<184, 256, 0, stream>>>(W1, W2, O1, O2, p1, p2, p3, p4);
    const int nb = (N + 63) / 64;
    k1_kernel<<<nb, 256, 0, stream>>>(feats, p1, p2, b1, b2, a_jk, a_main,
                                      wref, wax, batt, wsm, N);
    k2_kernel<<<nb, 256, 0, stream>>>(feats, wsm, p3, p4, bo1, a_out, bo2,
                                      (float*)d_out, N);
}